// Round 1
// baseline (260.579 us; speedup 1.0000x reference)
//
#include <hip/hip_runtime.h>

#define HH 128
#define WW 128
#define CC 64
#define CO 64
#define BB 4
#define GG 8
#define CG 8
#define KK 9
#define HW (HH*WW)

// Block: 256 threads, one (batch, output-row) per block. Grid = (128, 4) = 512 blocks = 2/CU.
// LDS: s_w[72][64] (18.4 KB) + s_col[72][128] (36.9 KB) = 55.3 KB -> 2 blocks/CU.
__global__ __launch_bounds__(256, 2)
void dcn_fused(const float* __restrict__ in, const float* __restrict__ off,
               const float* __restrict__ msk, const float* __restrict__ wt,
               const float* __restrict__ bias, float* __restrict__ out)
{
    __shared__ float s_w[72 * 64];    // [j][o], j = cg*9 + k
    __shared__ float s_col[72 * WW];  // [j][px]

    const int ho = blockIdx.x;
    const int b  = blockIdx.y;
    const int t  = threadIdx.x;

    const int o_row  = t >> 4;   // 0..15
    const int px_col = t & 15;   // 0..15
    const int o0 = o_row * 4;    // 4 contiguous output channels
    const int p0 = px_col * 8;   // 8 contiguous pixels

    float acc[4][8];
    #pragma unroll
    for (int i = 0; i < 4; ++i) {
        const float bv = bias[o0 + i];
        #pragma unroll
        for (int p = 0; p < 8; ++p) acc[i][p] = bv;
    }

    const float* inb = in + (long)b * CC * HW;

    for (int g = 0; g < GG; ++g) {
        __syncthreads();  // previous GEMM done before overwriting LDS

        // ---- stage weights: s_w[j*64+o] = wt[o*576 + g*72 + j] ----
        for (int idx = t; idx < 72 * 64; idx += 256) {
            const int j = idx >> 6;
            const int o = idx & 63;
            s_w[idx] = wt[o * 576 + g * 72 + j];
        }

        // ---- deformable im2col into LDS: 9 taps x 128 px pairs ----
        for (int pidx = t; pidx < KK * WW; pidx += 256) {
            const int k  = pidx >> 7;    // 0..8
            const int px = pidx & 127;
            const int ky = k / 3, kx = k - ky * 3;

            const int offc = (b * 144 + g * 18 + k * 2) * HW + ho * WW + px;
            const float dy = off[offc];
            const float dx = off[offc + HW];
            const float m  = msk[(b * 72 + g * 9 + k) * HW + ho * WW + px];

            const float py  = (float)(ho - 1 + ky) + dy;
            const float pxf = (float)(px - 1 + kx) + dx;
            const float y0f = floorf(py), x0f = floorf(pxf);
            const float ly = py - y0f, lx = pxf - x0f;
            const int y0 = (int)y0f, x0 = (int)x0f;
            const int y1 = y0 + 1,  x1 = x0 + 1;

            const float vy0 = (y0 >= 0 && y0 < HH) ? 1.f : 0.f;
            const float vy1 = (y1 >= 0 && y1 < HH) ? 1.f : 0.f;
            const float vx0 = (x0 >= 0 && x0 < WW) ? 1.f : 0.f;
            const float vx1 = (x1 >= 0 && x1 < WW) ? 1.f : 0.f;
            const int y0c = min(max(y0, 0), HH - 1), y1c = min(max(y1, 0), HH - 1);
            const int x0c = min(max(x0, 0), WW - 1), x1c = min(max(x1, 0), WW - 1);

            const float w00 = (1.f - ly) * (1.f - lx) * vy0 * vx0 * m;
            const float w01 = (1.f - ly) * lx         * vy0 * vx1 * m;
            const float w10 = ly         * (1.f - lx) * vy1 * vx0 * m;
            const float w11 = ly         * lx         * vy1 * vx1 * m;

            const int i00 = y0c * WW + x0c, i01 = y0c * WW + x1c;
            const int i10 = y1c * WW + x0c, i11 = y1c * WW + x1c;

            const float* ip = inb + (long)(g * CG) * HW;
            #pragma unroll
            for (int cg = 0; cg < CG; ++cg) {
                const float v = w00 * ip[i00] + w01 * ip[i01]
                              + w10 * ip[i10] + w11 * ip[i11];
                s_col[(cg * 9 + k) * WW + px] = v;
                ip += HW;
            }
        }

        __syncthreads();

        // ---- register-blocked GEMM: acc[4][8] += s_w[j][o0..o0+3] x s_col[j][p0..p0+7] ----
        #pragma unroll 4
        for (int j = 0; j < 72; ++j) {
            const float4 wv = *(const float4*)&s_w[j * 64 + o0];
            const float4 c0 = *(const float4*)&s_col[j * WW + p0];
            const float4 c1 = *(const float4*)&s_col[j * WW + p0 + 4];
            const float wvs[4] = {wv.x, wv.y, wv.z, wv.w};
            const float cvs[8] = {c0.x, c0.y, c0.z, c0.w, c1.x, c1.y, c1.z, c1.w};
            #pragma unroll
            for (int i = 0; i < 4; ++i)
                #pragma unroll
                for (int p = 0; p < 8; ++p)
                    acc[i][p] += wvs[i] * cvs[p];
        }
    }

    // ---- store: out[b, o, ho, p0..p0+7] ----
    #pragma unroll
    for (int i = 0; i < 4; ++i) {
        const long ob = ((long)(b * CO + o0 + i) * HH + ho) * WW + p0;
        *(float4*)&out[ob]     = make_float4(acc[i][0], acc[i][1], acc[i][2], acc[i][3]);
        *(float4*)&out[ob + 4] = make_float4(acc[i][4], acc[i][5], acc[i][6], acc[i][7]);
    }
}

extern "C" void kernel_launch(void* const* d_in, const int* in_sizes, int n_in,
                              void* d_out, int out_size, void* d_ws, size_t ws_size,
                              hipStream_t stream) {
    const float* in   = (const float*)d_in[0];
    const float* off  = (const float*)d_in[1];
    const float* msk  = (const float*)d_in[2];
    const float* wt   = (const float*)d_in[3];
    const float* bias = (const float*)d_in[4];
    float* out = (float*)d_out;

    dim3 grid(HH, BB);
    dcn_fused<<<grid, 256, 0, stream>>>(in, off, msk, wt, bias, out);
}

// Round 2
// 227.570 us; speedup vs baseline: 1.1451x; 1.1451x over previous
//
#include <hip/hip_runtime.h>

#define HH 128
#define WW 128
#define CC 64
#define CO 64
#define BB 4
#define GG 8
#define CG 8
#define KK 9
#define HW (HH*WW)
#define PXT 64        // px per block tile
#define JJ 72         // K-slice per group = CG*KK

// ---- pre-kernel: transpose weight [64][576] -> wt_t[(g*72+j)*64+o] ----
__global__ __launch_bounds__(256)
void wt_transpose(const float* __restrict__ wt, float* __restrict__ wt_t) {
    const int tid = blockIdx.x * 256 + threadIdx.x;   // 36864 total
    if (tid >= 576 * 64) return;
    const int o = tid & 63;
    const int r = tid >> 6;          // g*72 + j
    wt_t[tid] = wt[o * 576 + r];
}

// Block: 256 threads, tile = (b, ho, 64 px). Grid = (2,128,4) = 1024 blocks.
// LDS: s_w[72][64] + s_col[72][64] = 36.9 KB -> 4 blocks/CU -> 16 waves/CU.
__global__ __launch_bounds__(256, 4)
void dcn_fused(const float* __restrict__ in, const float* __restrict__ off,
               const float* __restrict__ msk, const float* __restrict__ wt_t,
               const float* __restrict__ bias, float* __restrict__ out)
{
    __shared__ float s_w[JJ * 64];    // [j][o]
    __shared__ float s_col[JJ * PXT]; // [j][px_local]

    const int pxbase = blockIdx.x * PXT;
    const int ho = blockIdx.y;
    const int b  = blockIdx.z;
    const int t  = threadIdx.x;

    const int o0 = (t >> 4) * 4;     // 4 contiguous output channels
    const int p0 = (t & 15) * 4;     // 4 contiguous local pixels

    float acc[4][4];
    #pragma unroll
    for (int i = 0; i < 4; ++i) {
        const float bv = bias[o0 + i];
        #pragma unroll
        for (int p = 0; p < 4; ++p) acc[i][p] = bv;
    }

    const float* inb = in + b * CC * HW;

    for (int g = 0; g < GG; ++g) {
        __syncthreads();  // previous GEMM done before overwriting LDS

        // ---- stage weights (coalesced float4 from transposed layout) ----
        {
            const float4* wsrc = (const float4*)(wt_t + g * (JJ * 64));
            float4* wdst = (float4*)s_w;
            #pragma unroll
            for (int idx = t; idx < JJ * 16; idx += 256) wdst[idx] = wsrc[idx];
        }

        // ---- deformable im2col into LDS: 9 taps x 64 px ----
        for (int pidx = t; pidx < KK * PXT; pidx += 256) {
            const int k  = pidx >> 6;        // 0..8
            const int pl = pidx & 63;        // local px
            const int px = pxbase + pl;
            const int ky = k / 3, kx = k - ky * 3;

            const int offc = (b * 144 + g * 18 + k * 2) * HW + ho * WW + px;
            const float dy = off[offc];
            const float dx = off[offc + HW];
            const float m  = msk[(b * 72 + g * 9 + k) * HW + ho * WW + px];

            const float py  = (float)(ho - 1 + ky) + dy;
            const float pxf = (float)(px - 1 + kx) + dx;
            const float y0f = floorf(py), x0f = floorf(pxf);
            const float ly = py - y0f, lx = pxf - x0f;
            const int y0 = (int)y0f, x0 = (int)x0f;
            const int y1 = y0 + 1,  x1 = x0 + 1;

            const float vy0 = (y0 >= 0 && y0 < HH) ? 1.f : 0.f;
            const float vy1 = (y1 >= 0 && y1 < HH) ? 1.f : 0.f;
            const float vx0 = (x0 >= 0 && x0 < WW) ? 1.f : 0.f;
            const float vx1 = (x1 >= 0 && x1 < WW) ? 1.f : 0.f;
            const int y0c = min(max(y0, 0), HH - 1), y1c = min(max(y1, 0), HH - 1);
            const int x0c = min(max(x0, 0), WW - 1), x1c = min(max(x1, 0), WW - 1);

            const float w00 = (1.f - ly) * (1.f - lx) * vy0 * vx0 * m;
            const float w01 = (1.f - ly) * lx         * vy0 * vx1 * m;
            const float w10 = ly         * (1.f - lx) * vy1 * vx0 * m;
            const float w11 = ly         * lx         * vy1 * vx1 * m;

            const int i00 = y0c * WW + x0c, i01 = y0c * WW + x1c;
            const int i10 = y1c * WW + x0c, i11 = y1c * WW + x1c;

            const float* ip = inb + g * CG * HW;
            #pragma unroll
            for (int cg = 0; cg < CG; ++cg) {
                const float v = w00 * ip[i00] + w01 * ip[i01]
                              + w10 * ip[i10] + w11 * ip[i11];
                s_col[(cg * 9 + k) * PXT + pl] = v;
                ip += HW;
            }
        }

        __syncthreads();

        // ---- register-blocked GEMM: acc[4][4] += s_w[j][o0..] x s_col[j][p0..] ----
        #pragma unroll 8
        for (int j = 0; j < JJ; ++j) {
            const float4 wv = *(const float4*)&s_w[j * 64 + o0];
            const float4 cv = *(const float4*)&s_col[j * PXT + p0];
            const float wvs[4] = {wv.x, wv.y, wv.z, wv.w};
            const float cvs[4] = {cv.x, cv.y, cv.z, cv.w};
            #pragma unroll
            for (int i = 0; i < 4; ++i)
                #pragma unroll
                for (int p = 0; p < 4; ++p)
                    acc[i][p] += wvs[i] * cvs[p];
        }
    }

    // ---- store: out[b, o0+i, ho, pxbase+p0 .. +3] ----
    #pragma unroll
    for (int i = 0; i < 4; ++i) {
        const int ob = ((b * CO + o0 + i) * HH + ho) * WW + pxbase + p0;
        *(float4*)&out[ob] = make_float4(acc[i][0], acc[i][1], acc[i][2], acc[i][3]);
    }
}

extern "C" void kernel_launch(void* const* d_in, const int* in_sizes, int n_in,
                              void* d_out, int out_size, void* d_ws, size_t ws_size,
                              hipStream_t stream) {
    const float* in   = (const float*)d_in[0];
    const float* off  = (const float*)d_in[1];
    const float* msk  = (const float*)d_in[2];
    const float* wt   = (const float*)d_in[3];
    const float* bias = (const float*)d_in[4];
    float* out  = (float*)d_out;
    float* wt_t = (float*)d_ws;   // 576*64*4 = 147456 B

    wt_transpose<<<144, 256, 0, stream>>>(wt, wt_t);

    dim3 grid(WW / PXT, HH, BB);
    dcn_fused<<<grid, 256, 0, stream>>>(in, off, msk, wt_t, bias, out);
}

// Round 3
// 216.129 us; speedup vs baseline: 1.2057x; 1.0529x over previous
//
#include <hip/hip_runtime.h>

#define HH 128
#define WW 128
#define CC 64
#define CO 64
#define BB 4
#define GG 8
#define CG 8
#define KK 9
#define HW (HH*WW)
#define PXT 64
#define NC 3            // k-chunks of 32 per group (72 padded to 96)
#define FRAG 512        // shorts per fragment tile: 64 lanes * 8

typedef __attribute__((ext_vector_type(8))) short short8;
typedef __attribute__((ext_vector_type(4))) float floatx4;

__device__ inline short f2bf(float f) {
    union { float f; unsigned u; } v; v.f = f;
    return (short)((v.u + 0x7FFF + ((v.u >> 16) & 1)) >> 16);
}

// ---- pre-kernel: pack weights into MFMA A-fragment order, bf16 ----
// wf[((g*3 + c)*4 + ot)*512 + L*8 + j] = bf16( W[o=ot*16+(L&15)][k=c*32+(L>>4)*8+j] )
// k = cg*9 + kk within group g (k>=72 -> 0 pad).
__global__ __launch_bounds__(256)
void wt_prepack(const float* __restrict__ wt, short* __restrict__ wf) {
    const int tid = blockIdx.x * 256 + threadIdx.x;   // 96*512 = 49152
    if (tid >= GG * NC * 4 * FRAG) return;
    const int j  = tid & 7;
    const int L  = (tid >> 3) & 63;
    const int fid = tid >> 9;          // (g*3+c)*4+ot
    const int ot = fid & 3;
    const int gc = fid >> 2;           // g*3+c
    const int c  = gc % 3;
    const int g  = gc / 3;
    const int kl = c * 32 + (L >> 4) * 8 + j;
    const int o  = ot * 16 + (L & 15);
    float val = 0.f;
    if (kl < 72) {
        const int cg = kl / 9;
        const int kk = kl - cg * 9;
        val = wt[o * 576 + (g * 8 + cg) * 9 + kk];
    }
    wf[tid] = f2bf(val);
}

// Block: 256 thr / 4 waves, tile = (b, ho, 64 px) -> 64o x 64px output.
// Grid (2,128,4)=1024. LDS: s_w 12.3K + s_col 12.3K + bias = ~25 KB.
__global__ __launch_bounds__(256, 4)
void dcn_fused(const float* __restrict__ in, const float* __restrict__ off,
               const float* __restrict__ msk, const short* __restrict__ wf,
               const float* __restrict__ bias, float* __restrict__ out)
{
    __shared__ short s_w[NC * 4 * FRAG];     // A-fragments [c][ot][lane][8]
    __shared__ short s_col[NC * 4 * FRAG];   // B-fragments [c][pt][lane][8]
    __shared__ float s_bias[64];

    const int pxbase = blockIdx.x * PXT;
    const int ho = blockIdx.y;
    const int b  = blockIdx.z;
    const int t  = threadIdx.x;
    const int w    = t >> 6;     // wave id -> px strip
    const int lane = t & 63;

    if (t < 64) s_bias[t] = bias[t];
    // zero col pad (k_local 72..95: chunk c=2, q=1..3) once; im2col never touches it
    for (int idx = t; idx < 768; idx += 256) {
        const int pt = idx / 192, r = idx - pt * 192;
        ((int*)s_col)[(8 + pt) * 256 + 64 + r] = 0;
    }
    __syncthreads();

    floatx4 acc[4];
    #pragma unroll
    for (int ot = 0; ot < 4; ++ot) {
        #pragma unroll
        for (int r = 0; r < 4; ++r)
            acc[ot][r] = s_bias[ot * 16 + (lane >> 4) * 4 + r];
    }

    const float* inb = in + b * CC * HW;

    for (int g = 0; g < GG; ++g) {
        __syncthreads();  // previous GEMM done reading LDS

        // ---- stage weight fragments: straight coalesced 16B copies ----
        {
            const short8* wsrc = (const short8*)(wf + g * (NC * 4 * FRAG));
            short8* wdst = (short8*)s_w;
            #pragma unroll
            for (int i = t; i < NC * 4 * 64; i += 256) wdst[i] = wsrc[i];
        }

        // ---- deformable im2col -> bf16 B-fragments in LDS ----
        for (int pidx = t; pidx < KK * PXT; pidx += 256) {
            const int kk = pidx >> 6;        // 0..8 (wave-uniform)
            const int pl = pidx & 63;
            const int px = pxbase + pl;
            const int ky = kk / 3, kx = kk - ky * 3;

            const int offc = (b * 144 + g * 18 + kk * 2) * HW + ho * WW + px;
            const float dy = off[offc];
            const float dx = off[offc + HW];
            const float m  = msk[(b * 72 + g * 9 + kk) * HW + ho * WW + px];

            const float py  = (float)(ho - 1 + ky) + dy;
            const float pxf = (float)(px - 1 + kx) + dx;
            const float y0f = floorf(py), x0f = floorf(pxf);
            const float ly = py - y0f, lx = pxf - x0f;
            const int y0 = (int)y0f, x0 = (int)x0f;
            const int y1 = y0 + 1,  x1 = x0 + 1;

            const float vy0 = (y0 >= 0 && y0 < HH) ? 1.f : 0.f;
            const float vy1 = (y1 >= 0 && y1 < HH) ? 1.f : 0.f;
            const float vx0 = (x0 >= 0 && x0 < WW) ? 1.f : 0.f;
            const float vx1 = (x1 >= 0 && x1 < WW) ? 1.f : 0.f;
            const int y0c = min(max(y0, 0), HH - 1), y1c = min(max(y1, 0), HH - 1);
            const int x0c = min(max(x0, 0), WW - 1), x1c = min(max(x1, 0), WW - 1);

            const float w00 = (1.f - ly) * (1.f - lx) * vy0 * vx0 * m;
            const float w01 = (1.f - ly) * lx         * vy0 * vx1 * m;
            const float w10 = ly         * (1.f - lx) * vy1 * vx0 * m;
            const float w11 = ly         * lx         * vy1 * vx1 * m;

            const int i00 = y0c * WW + x0c, i01 = y0c * WW + x1c;
            const int i10 = y1c * WW + x0c, i11 = y1c * WW + x1c;

            const int pt = pl >> 4, n = pl & 15;
            const float* ip = inb + g * CG * HW;
            #pragma unroll
            for (int cg = 0; cg < CG; ++cg) {
                const float v = w00 * ip[i00] + w01 * ip[i01]
                              + w10 * ip[i10] + w11 * ip[i11];
                const int kl = cg * 9 + kk;
                const int c = kl >> 5, rem = kl & 31;
                const int q = rem >> 3, jj = rem & 7;
                s_col[((c * 4 + pt) * 64 + q * 16 + n) * 8 + jj] = f2bf(v);
                ip += HW;
            }
        }

        __syncthreads();

        // ---- MFMA GEMM: wave w owns px strip w*16..w*16+15, all 64 o ----
        #pragma unroll
        for (int c = 0; c < NC; ++c) {
            const short8 bfr = *(const short8*)&s_col[((c * 4 + w) * 64 + lane) * 8];
            #pragma unroll
            for (int ot = 0; ot < 4; ++ot) {
                const short8 afr = *(const short8*)&s_w[((c * 4 + ot) * 64 + lane) * 8];
                acc[ot] = __builtin_amdgcn_mfma_f32_16x16x32_bf16(afr, bfr, acc[ot], 0, 0, 0);
            }
        }
    }

    // ---- epilogue: D row = o = ot*16 + (lane>>4)*4 + r, col = px = base + w*16 + (lane&15) ----
    const int q = lane >> 4, n = lane & 15;
    const int px = pxbase + w * 16 + n;
    #pragma unroll
    for (int ot = 0; ot < 4; ++ot) {
        #pragma unroll
        for (int r = 0; r < 4; ++r) {
            const int o = ot * 16 + q * 4 + r;
            out[((b * CO + o) * HH + ho) * WW + px] = acc[ot][r];
        }
    }
}

extern "C" void kernel_launch(void* const* d_in, const int* in_sizes, int n_in,
                              void* d_out, int out_size, void* d_ws, size_t ws_size,
                              hipStream_t stream) {
    const float* in   = (const float*)d_in[0];
    const float* off  = (const float*)d_in[1];
    const float* msk  = (const float*)d_in[2];
    const float* wt   = (const float*)d_in[3];
    const float* bias = (const float*)d_in[4];
    float* out = (float*)d_out;
    short* wf  = (short*)d_ws;    // 49152 shorts = 96 KB

    wt_prepack<<<192, 256, 0, stream>>>(wt, wf);

    dim3 grid(WW / PXT, HH, BB);
    dcn_fused<<<grid, 256, 0, stream>>>(in, off, msk, wf, bias, out);
}

// Round 4
// 155.840 us; speedup vs baseline: 1.6721x; 1.3869x over previous
//
#include <hip/hip_runtime.h>

#define HH 128
#define WW 128
#define CC 64
#define CO 64
#define BB 4
#define GG 8
#define CG 8
#define KK 9
#define HW (HH*WW)
#define PXT 32
#define NC 3            // k'-chunks of 32 (72 padded to 96)
#define FRAG 512        // shorts per 64-lane fragment tile

typedef __attribute__((ext_vector_type(8))) short short8;
typedef __attribute__((ext_vector_type(4))) float floatx4;

union S8I { short8 s; int i[4]; };

__device__ inline short f2bf(float f) {
    union { float f; unsigned u; } v; v.f = f;
    return (short)((v.u + 0x7FFF + ((v.u >> 16) & 1)) >> 16);
}
__device__ inline unsigned rnd_bf(float f) {   // rounded, bf16 in bits [31:16]
    union { float f; unsigned u; } v; v.f = f;
    return v.u + 0x7FFF + ((v.u >> 16) & 1);
}
__device__ inline float bflo(int e) { union { int i; float f; } u; u.i = e << 16; return u.f; }
__device__ inline float bfhi(int e) { union { int i; float f; } u; u.i = e & 0xffff0000; return u.f; }

// ---- pre-kernel 1: weights -> A-fragments, k' = kk*8 + cg ordering, bf16 ----
__global__ __launch_bounds__(256)
void wt_prepack(const float* __restrict__ wt, short* __restrict__ wf) {
    const int tid = blockIdx.x * 256 + threadIdx.x;   // 96*512 = 49152
    if (tid >= GG * NC * 4 * FRAG) return;
    const int j  = tid & 7;
    const int L  = (tid >> 3) & 63;
    const int fid = tid >> 9;
    const int ot = fid & 3;
    const int gc = fid >> 2;
    const int c  = gc % 3;
    const int g  = gc / 3;
    const int kp = c * 32 + (L >> 4) * 8 + j;   // k'
    const int o  = ot * 16 + (L & 15);
    float val = 0.f;
    if (kp < 72) {
        const int kk = kp >> 3;
        const int cg = kp & 7;
        val = wt[o * 576 + (g * 8 + cg) * 9 + kk];
    }
    wf[tid] = f2bf(val);
}

// ---- pre-kernel 2: input NCHW f32 -> [b][g][y*W+x][cg] bf16 (16B per pixel-group) ----
__global__ __launch_bounds__(256)
void in_transpose(const float* __restrict__ in, short* __restrict__ in_t) {
    const int p = blockIdx.x * 256 + threadIdx.x;   // 0..HW-1
    const int g = blockIdx.y, b = blockIdx.z;
    const float* src = in + (b * CC + g * CG) * HW + p;
    short8 v;
    #pragma unroll
    for (int cg = 0; cg < CG; ++cg) v[cg] = f2bf(src[cg * HW]);
    *(short8*)(in_t + ((b * GG + g) * HW + p) * 8) = v;
}

// Block: 256 thr / 4 waves, tile = (b, ho, 32 px) -> 64o x 32px. Grid (4,128,4)=2048.
// LDS: s_w 12K + s_col 6K + bias = 18.6 KB.
__global__ __launch_bounds__(256, 6)
void dcn_fused(const short* __restrict__ in_t, const float* __restrict__ off,
               const float* __restrict__ msk, const short* __restrict__ wf,
               const float* __restrict__ bias, float* __restrict__ out)
{
    __shared__ short s_w[NC * 4 * FRAG];     // A-frags [c][ot][lane][8]
    __shared__ short s_col[NC * 2 * FRAG];   // B-frags [c][pt][lane][8]
    __shared__ float s_bias[64];

    const int pxbase = blockIdx.x * PXT;
    const int ho = blockIdx.y;
    const int b  = blockIdx.z;
    const int t  = threadIdx.x;
    const int w = t >> 6, lane = t & 63;
    const int s  = w & 1;     // px strip (0..1)
    const int oh = w >> 1;    // ot half: ot = oh*2 + i

    if (t < 64) s_bias[t] = bias[t];
    // zero k' pad rows (c=2, q=1..3) once; never written in the g-loop
    for (int idx = t; idx < 384; idx += 256) {
        const int pt = idx / 192, r = idx - pt * 192;
        ((int*)s_col)[(4 + pt) * 256 + 64 + r] = 0;
    }
    __syncthreads();

    floatx4 acc[2];
    #pragma unroll
    for (int i = 0; i < 2; ++i)
        #pragma unroll
        for (int r = 0; r < 4; ++r)
            acc[i][r] = s_bias[(oh * 2 + i) * 16 + (lane >> 4) * 4 + r];

    const short* inb = in_t + (long)b * GG * HW * 8;

    for (int g = 0; g < GG; ++g) {
        __syncthreads();  // previous GEMM done reading LDS

        // ---- stage weight fragments (coalesced 16B) ----
        {
            const short8* wsrc = (const short8*)(wf + g * (NC * 4 * FRAG));
            short8* wdst = (short8*)s_w;
            #pragma unroll
            for (int i = t; i < NC * 4 * 64; i += 256) wdst[i] = wsrc[i];
        }

        // ---- deformable im2col: 1 lane = 1 (tap, px); 4x16B gathers for all 8 ch ----
        const short* ing = inb + g * HW * 8;
        for (int pidx = t; pidx < KK * PXT; pidx += 256) {
            const int kk = pidx >> 5;        // 0..8
            const int pl = pidx & 31;
            const int px = pxbase + pl;
            const int ky = kk / 3, kx = kk - ky * 3;

            const int offc = (b * 144 + g * 18 + kk * 2) * HW + ho * WW + px;
            const float dy = off[offc];
            const float dx = off[offc + HW];
            const float m  = msk[(b * 72 + g * 9 + kk) * HW + ho * WW + px];

            const float py  = (float)(ho - 1 + ky) + dy;
            const float pxf = (float)(px - 1 + kx) + dx;
            const float y0f = floorf(py), x0f = floorf(pxf);
            const float ly = py - y0f, lx = pxf - x0f;
            const int y0 = (int)y0f, x0 = (int)x0f;
            const int y1 = y0 + 1,  x1 = x0 + 1;

            const float vy0 = (y0 >= 0 && y0 < HH) ? 1.f : 0.f;
            const float vy1 = (y1 >= 0 && y1 < HH) ? 1.f : 0.f;
            const float vx0 = (x0 >= 0 && x0 < WW) ? 1.f : 0.f;
            const float vx1 = (x1 >= 0 && x1 < WW) ? 1.f : 0.f;
            const int y0c = min(max(y0, 0), HH - 1), y1c = min(max(y1, 0), HH - 1);
            const int x0c = min(max(x0, 0), WW - 1), x1c = min(max(x1, 0), WW - 1);

            const float w00 = (1.f - ly) * (1.f - lx) * vy0 * vx0 * m;
            const float w01 = (1.f - ly) * lx         * vy0 * vx1 * m;
            const float w10 = ly         * (1.f - lx) * vy1 * vx0 * m;
            const float w11 = ly         * lx         * vy1 * vx1 * m;

            S8I u00, u01, u10, u11;
            u00.s = *(const short8*)(ing + (y0c * WW + x0c) * 8);
            u01.s = *(const short8*)(ing + (y0c * WW + x1c) * 8);
            u10.s = *(const short8*)(ing + (y1c * WW + x0c) * 8);
            u11.s = *(const short8*)(ing + (y1c * WW + x1c) * 8);

            S8I res;
            #pragma unroll
            for (int pc = 0; pc < 4; ++pc) {
                const int e00 = u00.i[pc], e01 = u01.i[pc];
                const int e10 = u10.i[pc], e11 = u11.i[pc];
                const float vx_ = w00 * bflo(e00) + w01 * bflo(e01)
                                + w10 * bflo(e10) + w11 * bflo(e11);
                const float vy_ = w00 * bfhi(e00) + w01 * bfhi(e01)
                                + w10 * bfhi(e10) + w11 * bfhi(e11);
                res.i[pc] = (int)__builtin_amdgcn_perm(rnd_bf(vy_), rnd_bf(vx_), 0x07060302u);
            }

            // k' = kk*8 + cg -> one contiguous 16B fragment row
            const int c = kk >> 2, q = kk & 3;
            const int pt = pl >> 4, n = pl & 15;
            *(short8*)(s_col + ((c * 2 + pt) * 64 + q * 16 + n) * 8) = res.s;
        }

        __syncthreads();

        // ---- MFMA: wave (s,oh): px strip s, out channels oh*32..+31 ----
        #pragma unroll
        for (int c = 0; c < NC; ++c) {
            const short8 bfr = *(const short8*)&s_col[((c * 2 + s) * 64 + lane) * 8];
            #pragma unroll
            for (int i = 0; i < 2; ++i) {
                const short8 afr = *(const short8*)&s_w[((c * 4 + oh * 2 + i) * 64 + lane) * 8];
                acc[i] = __builtin_amdgcn_mfma_f32_16x16x32_bf16(afr, bfr, acc[i], 0, 0, 0);
            }
        }
    }

    // ---- epilogue ----
    const int q4 = lane >> 4, n = lane & 15;
    const int px = pxbase + s * 16 + n;
    #pragma unroll
    for (int i = 0; i < 2; ++i)
        #pragma unroll
        for (int r = 0; r < 4; ++r) {
            const int o = (oh * 2 + i) * 16 + q4 * 4 + r;
            out[((b * CO + o) * HH + ho) * WW + px] = acc[i][r];
        }
}

extern "C" void kernel_launch(void* const* d_in, const int* in_sizes, int n_in,
                              void* d_out, int out_size, void* d_ws, size_t ws_size,
                              hipStream_t stream) {
    const float* in   = (const float*)d_in[0];
    const float* off  = (const float*)d_in[1];
    const float* msk  = (const float*)d_in[2];
    const float* wt   = (const float*)d_in[3];
    const float* bias = (const float*)d_in[4];
    float* out = (float*)d_out;
    short* wf   = (short*)d_ws;            // 49152 shorts = 96 KB
    short* in_t = (short*)d_ws + 49152;    // 4*8*16384*8 shorts = 8 MB

    wt_prepack<<<192, 256, 0, stream>>>(wt, wf);
    in_transpose<<<dim3(HW / 256, GG, BB), 256, 0, stream>>>(in, in_t);

    dim3 grid(WW / PXT, HH, BB);
    dcn_fused<<<grid, 256, 0, stream>>>(in_t, off, msk, wf, bias, out);
}

// Round 5
// 146.395 us; speedup vs baseline: 1.7800x; 1.0645x over previous
//
#include <hip/hip_runtime.h>

#define HH 128
#define WW 128
#define CC 64
#define CO 64
#define BB 4
#define GG 8
#define CG 8
#define KK 9
#define HW (HH*WW)
#define PXT 16
#define NC 3            // k'-chunks of 32 (72 padded to 96)
#define FRAG 512        // shorts per 64-lane fragment tile
#define NPOS (GG*KK*PXT)   // 1152 positions per block

typedef __attribute__((ext_vector_type(8))) short short8;
typedef __attribute__((ext_vector_type(4))) float floatx4;

union S8I { short8 s; int i[4]; };

__device__ inline short f2bf(float f) {
    union { float f; unsigned u; } v; v.f = f;
    return (short)((v.u + 0x7FFF + ((v.u >> 16) & 1)) >> 16);
}
__device__ inline unsigned rnd_bf(float f) {   // rounded, bf16 in bits [31:16]
    union { float f; unsigned u; } v; v.f = f;
    return v.u + 0x7FFF + ((v.u >> 16) & 1);
}
__device__ inline float bflo(int e) { union { int i; float f; } u; u.i = e << 16; return u.f; }
__device__ inline float bfhi(int e) { union { int i; float f; } u; u.i = e & 0xffff0000; return u.f; }

// ---- pre-kernel 1: weights -> A-fragments, k' = kk*8 + cg ordering, bf16 ----
__global__ __launch_bounds__(256)
void wt_prepack(const float* __restrict__ wt, short* __restrict__ wf) {
    const int tid = blockIdx.x * 256 + threadIdx.x;   // 96*512 = 49152
    if (tid >= GG * NC * 4 * FRAG) return;
    const int j  = tid & 7;
    const int L  = (tid >> 3) & 63;
    const int fid = tid >> 9;
    const int ot = fid & 3;
    const int gc = fid >> 2;
    const int c  = gc % 3;
    const int g  = gc / 3;
    const int kp = c * 32 + (L >> 4) * 8 + j;   // k'
    const int o  = ot * 16 + (L & 15);
    float val = 0.f;
    if (kp < 72) {
        const int kk = kp >> 3;
        const int cg = kp & 7;
        val = wt[o * 576 + (g * 8 + cg) * 9 + kk];
    }
    wf[tid] = f2bf(val);
}

// ---- pre-kernel 2: input NCHW f32 -> [b][g][y*W+x][cg] bf16 (16B per pixel-group) ----
__global__ __launch_bounds__(256)
void in_transpose(const float* __restrict__ in, short* __restrict__ in_t) {
    const int p = blockIdx.x * 256 + threadIdx.x;   // 0..HW-1
    const int g = blockIdx.y, b = blockIdx.z;
    const float* src = in + (b * CC + g * CG) * HW + p;
    short8 v;
    #pragma unroll
    for (int cg = 0; cg < CG; ++cg) v[cg] = f2bf(src[cg * HW]);
    *(short8*)(in_t + ((b * GG + g) * HW + p) * 8) = v;
}

// Block: 256 thr / 4 waves, tile = (b, ho, 16 px) -> 64o x 16px. Grid (8,128,4)=4096.
// ONE barrier: flat 1152-position gather (all 8 groups) -> s_col (24 KB), then
// 24-step MFMA with A-frags straight from L2-hot global. Wave w owns ot=w.
__global__ __launch_bounds__(256, 4)
void dcn_fused(const short* __restrict__ in_t, const float* __restrict__ off,
               const float* __restrict__ msk, const short* __restrict__ wf,
               const float* __restrict__ bias, float* __restrict__ out)
{
    __shared__ short s_col[GG * NC * FRAG];   // [g][c][lane][8] = 24 KB

    const int pxbase = blockIdx.x * PXT;
    const int ho = blockIdx.y;
    const int b  = blockIdx.z;
    const int t  = threadIdx.x;
    const int w = t >> 6, lane = t & 63;

    // ---- prefetch ALL offset/mask values for this thread's positions (15 loads in flight) ----
    float pdy[5], pdx[5], pm[5];
    #pragma unroll
    for (int i = 0; i < 5; ++i) {
        const int pidx = t + i * 256;
        if (pidx < NPOS) {
            const int tc = pidx >> 4;           // 0..71 = g*9+kk
            const int g  = tc / 9, kk = tc - g * 9;
            const int px = pxbase + (pidx & 15);
            const int base = ho * WW + px;
            const int offc = (b * 144 + g * 18 + kk * 2) * HW + base;
            pdy[i] = off[offc];
            pdx[i] = off[offc + HW];
            pm[i]  = msk[(b * 72 + g * 9 + kk) * HW + base];
        }
    }

    // ---- zero k' pad rows (c=2, q>=1) for all g ----
    for (int idx = t; idx < 384; idx += 256) {
        const int g = idx / 48, l = (idx - g * 48) + 16;
        ((int4*)s_col)[(g * 3 + 2) * 64 + l] = make_int4(0, 0, 0, 0);
    }

    // ---- acc init from bias (C/D layout: row o = w*16 + q4*4 + r, col px = n16) ----
    const int q4 = lane >> 4, n16 = lane & 15;
    floatx4 acc0, acc1;
    #pragma unroll
    for (int r = 0; r < 4; ++r) { acc0[r] = bias[w * 16 + q4 * 4 + r]; acc1[r] = 0.f; }

    // ---- gather phase: no barriers, max MLP ----
    const short* inb = in_t + (long)b * GG * HW * 8;
    #pragma unroll
    for (int i = 0; i < 5; ++i) {
        const int pidx = t + i * 256;
        if (pidx < NPOS) {
            const int tc = pidx >> 4;
            const int g  = tc / 9, kk = tc - g * 9;
            const int pl = pidx & 15;
            const int px = pxbase + pl;
            const int ky = kk / 3, kx = kk - ky * 3;

            const float py  = (float)(ho - 1 + ky) + pdy[i];
            const float pxf = (float)(px - 1 + kx) + pdx[i];
            const float y0f = floorf(py), x0f = floorf(pxf);
            const float ly = py - y0f, lx = pxf - x0f;
            const int y0 = (int)y0f, x0 = (int)x0f;
            const int y1 = y0 + 1,  x1 = x0 + 1;

            const float vy0 = (y0 >= 0 && y0 < HH) ? 1.f : 0.f;
            const float vy1 = (y1 >= 0 && y1 < HH) ? 1.f : 0.f;
            const float vx0 = (x0 >= 0 && x0 < WW) ? 1.f : 0.f;
            const float vx1 = (x1 >= 0 && x1 < WW) ? 1.f : 0.f;
            const int y0c = min(max(y0, 0), HH - 1), y1c = min(max(y1, 0), HH - 1);
            const int x0c = min(max(x0, 0), WW - 1), x1c = min(max(x1, 0), WW - 1);

            const float m = pm[i];
            const float w00 = (1.f - ly) * (1.f - lx) * vy0 * vx0 * m;
            const float w01 = (1.f - ly) * lx         * vy0 * vx1 * m;
            const float w10 = ly         * (1.f - lx) * vy1 * vx0 * m;
            const float w11 = ly         * lx         * vy1 * vx1 * m;

            const short* ing = inb + g * (HW * 8);
            S8I u00, u01, u10, u11;
            u00.s = *(const short8*)(ing + (y0c * WW + x0c) * 8);
            u01.s = *(const short8*)(ing + (y0c * WW + x1c) * 8);
            u10.s = *(const short8*)(ing + (y1c * WW + x0c) * 8);
            u11.s = *(const short8*)(ing + (y1c * WW + x1c) * 8);

            S8I res;
            #pragma unroll
            for (int pc = 0; pc < 4; ++pc) {
                const int e00 = u00.i[pc], e01 = u01.i[pc];
                const int e10 = u10.i[pc], e11 = u11.i[pc];
                const float vx_ = w00 * bflo(e00) + w01 * bflo(e01)
                                + w10 * bflo(e10) + w11 * bflo(e11);
                const float vy_ = w00 * bfhi(e00) + w01 * bfhi(e01)
                                + w10 * bfhi(e10) + w11 * bfhi(e11);
                res.i[pc] = (int)__builtin_amdgcn_perm(rnd_bf(vy_), rnd_bf(vx_), 0x07060302u);
            }

            // k' = kk*8+cg -> chunk c=kk>>2, row q=kk&3, col pl: one 16B write
            const int c = kk >> 2, q = kk & 3;
            *(short8*)(s_col + ((g * 3 + c) * 64 + q * 16 + pl) * 8) = res.s;
        }
    }

    __syncthreads();   // the only barrier

    // ---- MFMA: 24 chunks, A-frags from L2-hot global, 2 acc chains ----
    #pragma unroll
    for (int gc = 0; gc < GG * NC; ++gc) {
        const short8 bfr = *(const short8*)&s_col[(gc * 64 + lane) * 8];
        const short8 afr = *(const short8*)&wf[((gc * 4 + w) * 64 + lane) * 8];
        if (gc & 1) acc1 = __builtin_amdgcn_mfma_f32_16x16x32_bf16(afr, bfr, acc1, 0, 0, 0);
        else        acc0 = __builtin_amdgcn_mfma_f32_16x16x32_bf16(afr, bfr, acc0, 0, 0, 0);
    }

    // ---- epilogue ----
    const int px = pxbase + n16;
    #pragma unroll
    for (int r = 0; r < 4; ++r) {
        const int o = w * 16 + q4 * 4 + r;
        out[((b * CO + o) * HH + ho) * WW + px] = acc0[r] + acc1[r];
    }
}

extern "C" void kernel_launch(void* const* d_in, const int* in_sizes, int n_in,
                              void* d_out, int out_size, void* d_ws, size_t ws_size,
                              hipStream_t stream) {
    const float* in   = (const float*)d_in[0];
    const float* off  = (const float*)d_in[1];
    const float* msk  = (const float*)d_in[2];
    const float* wt   = (const float*)d_in[3];
    const float* bias = (const float*)d_in[4];
    float* out = (float*)d_out;
    short* wf   = (short*)d_ws;            // 49152 shorts = 96 KB
    short* in_t = (short*)d_ws + 49152;    // 4*8*16384*8 shorts = 8 MB

    wt_prepack<<<192, 256, 0, stream>>>(wt, wf);
    in_transpose<<<dim3(HW / 256, GG, BB), 256, 0, stream>>>(in, in_t);

    dim3 grid(WW / PXT, HH, BB);
    dcn_fused<<<grid, 256, 0, stream>>>(in_t, off, msk, wf, bias, out);
}